// Round 8
// baseline (1253.944 us; speedup 1.0000x reference)
//
#include <hip/hip_runtime.h>
#include <cstdint>

constexpr int N_FEAT  = 8;
constexpr int E_FEAT  = 4;
constexpr int NUM_IN  = 2 * (N_FEAT + 2) + E_FEAT + 1;  // 25
constexpr int NUM_OUT = 2 * N_FEAT + E_FEAT;            // 20
constexpr int BLK     = 256;
constexpr int EPT     = 2;      // edges per thread
constexpr int RSTRIDE = 28;     // LDS row stride (25 padded to 7 float4s)

// Evidence trail (dispatch-us / VALUBusy):
//   SMEM weights (s_load->SGPR), EPT=1:   77 / 40%  -- lgkmcnt(0) drain convoys
//   VMEM weights (global->VGPR), EPT=1:  171 / 19%  -- 281 x ~200cy, no pipelining
//   LDS weights, EPT=1:                   70 / 44%  -- LDS return bus ~2x oversub
//   LDS weights, EPT=2 straight-line:   1054 /  3%  -- pre-RA scheduler interleaved
//       45 independent row blocks, pressure blew to 100s, RA spilled x/h wholesale
//       (3.5 GB scratch traffic at VGPR_Count=84).
// Fix this round: pin the schedule at ROW granularity with sched_barrier(0) so
// pressure stays ~140 (x0+x1=50, h<=48, 28 transient weights, addressing), and
// pin waves_per_eu(3,3) so the allocator targets the 170-VGPR/3-wave budget.

#define SBAR __builtin_amdgcn_sched_barrier(0);

#define REP25(F) F(0) F(1) F(2) F(3) F(4) F(5) F(6) F(7) F(8) F(9) F(10) F(11) \
                 F(12) F(13) F(14) F(15) F(16) F(17) F(18) F(19) F(20) F(21) F(22) F(23) F(24)
#define REP20(F) F(0) F(1) F(2) F(3) F(4) F(5) F(6) F(7) F(8) F(9) F(10) F(11) \
                 F(12) F(13) F(14) F(15) F(16) F(17) F(18) F(19)

#define DECLX(j) float x0_##j, x1_##j;
#define DECLH(j) float h0_##j, h1_##j;
#define DECLY(j) float y0_##j, y1_##j;

// Gather 25 features for edge ee into named scalars P##0..P##24.
#define LOADX(ee, P)                                                          \
  {                                                                           \
    const float4* A4_ = reinterpret_cast<const float4*>(a_data) + 2 * (size_t)(ee); \
    const float4* B4_ = reinterpret_cast<const float4*>(b_data) + 2 * (size_t)(ee); \
    const float4 A0_ = A4_[0], A1_ = A4_[1];                                  \
    const float4 Bv0_ = B4_[0], Bv1_ = B4_[1];                                \
    const float4 Ev_ = reinterpret_cast<const float4*>(e_data)[(ee)];         \
    P##0  = r[(ee)];                                                          \
    P##1  = A0_.x;  P##2  = A0_.y;  P##3  = A0_.z;  P##4  = A0_.w;            \
    P##5  = A1_.x;  P##6  = A1_.y;  P##7  = A1_.z;  P##8  = A1_.w;            \
    P##9  = a_mat[(ee)];                                                      \
    P##10 = a_inf[(ee)];                                                      \
    P##11 = Bv0_.x; P##12 = Bv0_.y; P##13 = Bv0_.z; P##14 = Bv0_.w;           \
    P##15 = Bv1_.x; P##16 = Bv1_.y; P##17 = Bv1_.z; P##18 = Bv1_.w;           \
    P##19 = b_mat[(ee)];                                                      \
    P##20 = b_inf[(ee)];                                                      \
    P##21 = Ev_.x;  P##22 = Ev_.y;  P##23 = Ev_.z;  P##24 = Ev_.w;            \
  }

// One output row j (7 aligned broadcast ds_read_b128 = 25 weights + pad),
// accumulated for BOTH edges, relu, into OA##j / OB##j. Ends with a
// scheduling fence so the next row cannot be hoisted into this one
// (pressure containment -- see header comment).
#define MLPROW(SW4, SB, j, XA, XB, OA, OB)                                    \
  {                                                                           \
    const float4 q0_ = SW4[(j)*7 + 0], q1_ = SW4[(j)*7 + 1];                  \
    const float4 q2_ = SW4[(j)*7 + 2], q3_ = SW4[(j)*7 + 3];                  \
    const float4 q4_ = SW4[(j)*7 + 4], q5_ = SW4[(j)*7 + 5];                  \
    const float4 q6_ = SW4[(j)*7 + 6];                                        \
    float aA_ = SB[(j)], aB_ = aA_;                                           \
    aA_ = fmaf(q0_.x, XA##0,  aA_);  aB_ = fmaf(q0_.x, XB##0,  aB_);          \
    aA_ = fmaf(q0_.y, XA##1,  aA_);  aB_ = fmaf(q0_.y, XB##1,  aB_);          \
    aA_ = fmaf(q0_.z, XA##2,  aA_);  aB_ = fmaf(q0_.z, XB##2,  aB_);          \
    aA_ = fmaf(q0_.w, XA##3,  aA_);  aB_ = fmaf(q0_.w, XB##3,  aB_);          \
    aA_ = fmaf(q1_.x, XA##4,  aA_);  aB_ = fmaf(q1_.x, XB##4,  aB_);          \
    aA_ = fmaf(q1_.y, XA##5,  aA_);  aB_ = fmaf(q1_.y, XB##5,  aB_);          \
    aA_ = fmaf(q1_.z, XA##6,  aA_);  aB_ = fmaf(q1_.z, XB##6,  aB_);          \
    aA_ = fmaf(q1_.w, XA##7,  aA_);  aB_ = fmaf(q1_.w, XB##7,  aB_);          \
    aA_ = fmaf(q2_.x, XA##8,  aA_);  aB_ = fmaf(q2_.x, XB##8,  aB_);          \
    aA_ = fmaf(q2_.y, XA##9,  aA_);  aB_ = fmaf(q2_.y, XB##9,  aB_);          \
    aA_ = fmaf(q2_.z, XA##10, aA_);  aB_ = fmaf(q2_.z, XB##10, aB_);          \
    aA_ = fmaf(q2_.w, XA##11, aA_);  aB_ = fmaf(q2_.w, XB##11, aB_);          \
    aA_ = fmaf(q3_.x, XA##12, aA_);  aB_ = fmaf(q3_.x, XB##12, aB_);          \
    aA_ = fmaf(q3_.y, XA##13, aA_);  aB_ = fmaf(q3_.y, XB##13, aB_);          \
    aA_ = fmaf(q3_.z, XA##14, aA_);  aB_ = fmaf(q3_.z, XB##14, aB_);          \
    aA_ = fmaf(q3_.w, XA##15, aA_);  aB_ = fmaf(q3_.w, XB##15, aB_);          \
    aA_ = fmaf(q4_.x, XA##16, aA_);  aB_ = fmaf(q4_.x, XB##16, aB_);          \
    aA_ = fmaf(q4_.y, XA##17, aA_);  aB_ = fmaf(q4_.y, XB##17, aB_);          \
    aA_ = fmaf(q4_.z, XA##18, aA_);  aB_ = fmaf(q4_.z, XB##18, aB_);          \
    aA_ = fmaf(q4_.w, XA##19, aA_);  aB_ = fmaf(q4_.w, XB##19, aB_);          \
    aA_ = fmaf(q5_.x, XA##20, aA_);  aB_ = fmaf(q5_.x, XB##20, aB_);          \
    aA_ = fmaf(q5_.y, XA##21, aA_);  aB_ = fmaf(q5_.y, XB##21, aB_);          \
    aA_ = fmaf(q5_.z, XA##22, aA_);  aB_ = fmaf(q5_.z, XB##22, aB_);          \
    aA_ = fmaf(q5_.w, XA##23, aA_);  aB_ = fmaf(q5_.w, XB##23, aB_);          \
    aA_ = fmaf(q6_.x, XA##24, aA_);  aB_ = fmaf(q6_.x, XB##24, aB_);          \
    OA##j = fmaxf(aA_, 0.0f);        OB##j = fmaxf(aB_, 0.0f);                \
  }                                                                           \
  SBAR

#define L1ROW(j) MLPROW(sW14, sB1, j, x0_, x1_, h0_, h1_)
#define L2ROW(j) MLPROW(sW24, sB2, j, h0_, h1_, y0_, y1_)

// Store the 20 outputs of edge ee (prefix P = y0_ / y1_).
#define STOREY(ee, P)                                                         \
  {                                                                           \
    float4* o0_ = reinterpret_cast<float4*>(out) + 2 * (size_t)(ee);          \
    o0_[0] = make_float4(P##0,  P##1,  P##2,  P##3);                          \
    o0_[1] = make_float4(P##4,  P##5,  P##6,  P##7);                          \
    float4* o1_ = reinterpret_cast<float4*>(out + (size_t)8 * E) + 2 * (size_t)(ee); \
    o1_[0] = make_float4(P##8,  P##9,  P##10, P##11);                         \
    o1_[1] = make_float4(P##12, P##13, P##14, P##15);                         \
    reinterpret_cast<float4*>(out + (size_t)16 * E)[(ee)] =                   \
        make_float4(P##16, P##17, P##18, P##19);                              \
  }

__global__ __launch_bounds__(BLK)
__attribute__((amdgpu_waves_per_eu(3, 3)))
void edge_mlp(
    const float* __restrict__ r,
    const float* __restrict__ a_data,
    const float* __restrict__ a_mat,
    const float* __restrict__ a_inf,
    const float* __restrict__ b_data,
    const float* __restrict__ b_mat,
    const float* __restrict__ b_inf,
    const float* __restrict__ e_data,
    const float* __restrict__ W1,   // (25,25) row-major fp32
    const float* __restrict__ B1,   // (25,)
    const float* __restrict__ W2,   // (20,25) row-major
    const float* __restrict__ B2,   // (20,)
    float*       __restrict__ out,  // fp32, 3 segments concatenated
    int E) {
  __shared__ __align__(16) float sW1[NUM_IN  * RSTRIDE];  // 700 floats
  __shared__ __align__(16) float sW2[NUM_OUT * RSTRIDE];  // 560 floats
  __shared__ float sB1[NUM_IN];
  __shared__ float sB2[NUM_OUT];

  const int tid = threadIdx.x;
  // ---- stage weights into LDS, rows padded to 28 floats (7 aligned f4) ----
  for (int idx = tid; idx < NUM_IN * NUM_IN; idx += BLK)
    sW1[(idx / NUM_IN) * RSTRIDE + (idx % NUM_IN)] = W1[idx];
  for (int idx = tid; idx < NUM_OUT * NUM_IN; idx += BLK)
    sW2[(idx / NUM_IN) * RSTRIDE + (idx % NUM_IN)] = W2[idx];
  if (tid < NUM_IN)  sB1[tid] = B1[tid];
  if (tid < NUM_OUT) sB2[tid] = B2[tid];
  __syncthreads();

  const float4* sW14 = reinterpret_cast<const float4*>(sW1);
  const float4* sW24 = reinterpret_cast<const float4*>(sW2);

  const int base = blockIdx.x * (BLK * EPT);
  const int e0   = base + tid;
  if (e0 >= E) return;
  int e1         = base + BLK + tid;
  const bool p1  = (e1 < E);
  if (!p1) e1 = e0;   // clamp: tail block's second-edge loads stay in-bounds

  // ---- gather features for both edges (named scalars) ----
  REP25(DECLX)
  LOADX(e0, x0_)
  LOADX(e1, x1_)
  SBAR   // keep the gather loads out of the row regions

  // ---- layer 1: 25 rows x 2 edges; each weight read ONCE per row pair ----
  REP25(DECLH)
  REP25(L1ROW)

  // ---- layer 2: 20 rows x 2 edges ----
  REP20(DECLY)
  REP20(L2ROW)

  // ---- store both edges ----
  STOREY(e0, y0_)
  if (p1) STOREY(e1, y1_)
}

extern "C" void kernel_launch(void* const* d_in, const int* in_sizes, int n_in,
                              void* d_out, int out_size, void* d_ws, size_t ws_size,
                              hipStream_t stream) {
  const float* r      = (const float*)d_in[0];
  const float* a_data = (const float*)d_in[1];
  const float* a_mat  = (const float*)d_in[2];
  const float* a_inf  = (const float*)d_in[3];
  const float* b_data = (const float*)d_in[4];
  const float* b_mat  = (const float*)d_in[5];
  const float* b_inf  = (const float*)d_in[6];
  const float* e_data = (const float*)d_in[7];
  const float* W1     = (const float*)d_in[8];
  const float* B1     = (const float*)d_in[9];
  const float* W2     = (const float*)d_in[10];
  const float* B2     = (const float*)d_in[11];
  int E = in_sizes[0];

  const int epb = BLK * EPT;
  edge_mlp<<<(E + epb - 1) / epb, BLK, 0, stream>>>(
      r, a_data, a_mat, a_inf, b_data, b_mat, b_inf, e_data,
      W1, B1, W2, B2, (float*)d_out, E);
}

// Round 9
// 193.974 us; speedup vs baseline: 6.4645x; 6.4645x over previous
//
#include <hip/hip_runtime.h>
#include <cstdint>

constexpr int N_FEAT  = 8;
constexpr int E_FEAT  = 4;
constexpr int NUM_IN  = 2 * (N_FEAT + 2) + E_FEAT + 1;  // 25
constexpr int NUM_OUT = 2 * N_FEAT + E_FEAT;            // 20
constexpr int BLK     = 256;

// Evidence trail (dispatch-us / VALUBusy):
//   SMEM weights (s_load->SGPR), EPT=1:   77 / 40%  -- lgkmcnt(0) drain convoys
//   VMEM weights (global->VGPR), EPT=1:  171 / 19%  -- 281 x ~200cy, no pipelining
//   LDS fp32 weights, EPT=1:              70 / 44%  -- LDS return bus saturated:
//       4 SIMDs x 315 ds_read_b128 x ~4.5cy = 5670 LDS-cy per 2250 FMA-cy
//       -> predicted VALU 40%, measured 44%.
//   EPT=2 (5 formulations):        spills (allocator pins VGPR<=85 ~ 6 waves/EU
//       regardless of waves_per_eu; x/h wholesale to scratch, 3.5-3.8 GB traffic).
// This round: keep the PROVEN EPT=1 structure, halve weight BYTES instead of
// doubling FMAs per byte. Weights in LDS as fp16, flat-packed (no row pad):
//   L1 = 79 ds_read_b128, L2 = 63 -> 142 reads/edge (vs 315). Biases move to
// the scalar path (uniform, 45 dwords, one-time). Consumption via
// (float)(_Float16) -> clang mad-mix fuses into v_fma_mix_f32 (fp32 accum).
// fp16 weight error ~2e-3 worst-case < 3.9e-3 absmax bound.

typedef _Float16 half8 __attribute__((ext_vector_type(8)));  // 16 B = 1 ds_read_b128

__global__ __launch_bounds__(BLK)
__attribute__((amdgpu_waves_per_eu(4, 8)))
void edge_mlp(
    const float* __restrict__ r,
    const float* __restrict__ a_data,
    const float* __restrict__ a_mat,
    const float* __restrict__ a_inf,
    const float* __restrict__ b_data,
    const float* __restrict__ b_mat,
    const float* __restrict__ b_inf,
    const float* __restrict__ e_data,
    const float* __restrict__ W1,   // (25,25) row-major fp32
    const float* __restrict__ B1,   // (25,)
    const float* __restrict__ W2,   // (20,25) row-major
    const float* __restrict__ B2,   // (20,)
    float*       __restrict__ out,  // fp32, 3 segments concatenated
    int E) {
  // Flat-packed fp16 weights; tails zero-padded so the last b128 is harmless.
  __shared__ __align__(16) _Float16 sW1h[632];   // 625 used, 79 x half8
  __shared__ __align__(16) _Float16 sW2h[504];   // 500 used, 63 x half8

  const int tid = threadIdx.x;
  if (tid < 7) sW1h[625 + tid] = (_Float16)0.f;
  if (tid < 4) sW2h[500 + tid] = (_Float16)0.f;
  for (int i = tid; i < 625; i += BLK) sW1h[i] = (_Float16)W1[i];
  for (int i = tid; i < 500; i += BLK) sW2h[i] = (_Float16)W2[i];
  __syncthreads();

  const int e = blockIdx.x * BLK + tid;
  if (e >= E) return;

  // ---- gather the 25 fp32 input features (round-6 proven-promoting form) ----
  const float4* a4 = reinterpret_cast<const float4*>(a_data) + 2 * (size_t)e;
  const float4* b4 = reinterpret_cast<const float4*>(b_data) + 2 * (size_t)e;
  float4 a0 = a4[0], a1 = a4[1];
  float4 b0 = b4[0], b1v = b4[1];
  float4 ev = reinterpret_cast<const float4*>(e_data)[e];

  float x[NUM_IN];
  x[0]  = r[e];
  x[1]  = a0.x; x[2]  = a0.y; x[3]  = a0.z; x[4]  = a0.w;
  x[5]  = a1.x; x[6]  = a1.y; x[7]  = a1.z; x[8]  = a1.w;
  x[9]  = a_mat[e];
  x[10] = a_inf[e];
  x[11] = b0.x; x[12] = b0.y; x[13] = b0.z; x[14] = b0.w;
  x[15] = b1v.x; x[16] = b1v.y; x[17] = b1v.z; x[18] = b1v.w;
  x[19] = b_mat[e];
  x[20] = b_inf[e];
  x[21] = ev.x; x[22] = ev.y; x[23] = ev.z; x[24] = ev.w;

  // ---- layer 1: flat fp16 stream, compile-time (row=d/25, col=d%25) ----
  float acc[NUM_IN];
#pragma unroll
  for (int j = 0; j < NUM_IN; ++j) acc[j] = B1[j];   // uniform -> scalar loads
  {
    const half8* w8 = reinterpret_cast<const half8*>(sW1h);
#pragma unroll
    for (int i = 0; i < 79; ++i) {
      const half8 w = w8[i];
#pragma unroll
      for (int k = 0; k < 8; ++k) {
        const int d = 8 * i + k;
        if (d < 625)   // compile-time guard (folds after unroll)
          acc[d / NUM_IN] = fmaf((float)w[k], x[d % NUM_IN], acc[d / NUM_IN]);
      }
    }
  }
  float h[NUM_IN];
#pragma unroll
  for (int j = 0; j < NUM_IN; ++j) h[j] = fmaxf(acc[j], 0.0f);

  // ---- layer 2: flat fp16 stream ----
  float acc2[NUM_OUT];
#pragma unroll
  for (int j = 0; j < NUM_OUT; ++j) acc2[j] = B2[j];
  {
    const half8* w8 = reinterpret_cast<const half8*>(sW2h);
#pragma unroll
    for (int i = 0; i < 63; ++i) {
      const half8 w = w8[i];
#pragma unroll
      for (int k = 0; k < 8; ++k) {
        const int d = 8 * i + k;
        if (d < 500)
          acc2[d / NUM_IN] = fmaf((float)w[k], h[d % NUM_IN], acc2[d / NUM_IN]);
      }
    }
  }

  float y[NUM_OUT];
#pragma unroll
  for (int j = 0; j < NUM_OUT; ++j) y[j] = fmaxf(acc2[j], 0.0f);

  // ---- store fp32 into the 3 concatenated output segments ----
  float4* o0 = reinterpret_cast<float4*>(out) + 2 * (size_t)e;            // (E,8)
  o0[0] = make_float4(y[0], y[1], y[2],  y[3]);
  o0[1] = make_float4(y[4], y[5], y[6],  y[7]);
  float4* o1 = reinterpret_cast<float4*>(out + (size_t)8 * E) + 2 * (size_t)e;  // (E,8)
  o1[0] = make_float4(y[8],  y[9],  y[10], y[11]);
  o1[1] = make_float4(y[12], y[13], y[14], y[15]);
  reinterpret_cast<float4*>(out + (size_t)16 * E)[e] =                    // (E,4)
      make_float4(y[16], y[17], y[18], y[19]);
}

extern "C" void kernel_launch(void* const* d_in, const int* in_sizes, int n_in,
                              void* d_out, int out_size, void* d_ws, size_t ws_size,
                              hipStream_t stream) {
  const float* r      = (const float*)d_in[0];
  const float* a_data = (const float*)d_in[1];
  const float* a_mat  = (const float*)d_in[2];
  const float* a_inf  = (const float*)d_in[3];
  const float* b_data = (const float*)d_in[4];
  const float* b_mat  = (const float*)d_in[5];
  const float* b_inf  = (const float*)d_in[6];
  const float* e_data = (const float*)d_in[7];
  const float* W1     = (const float*)d_in[8];
  const float* B1     = (const float*)d_in[9];
  const float* W2     = (const float*)d_in[10];
  const float* B2     = (const float*)d_in[11];
  int E = in_sizes[0];

  edge_mlp<<<(E + BLK - 1) / BLK, BLK, 0, stream>>>(
      r, a_data, a_mat, a_inf, b_data, b_mat, b_inf, e_data,
      W1, B1, W2, B2, (float*)d_out, E);
}